// Round 7
// baseline (414.145 us; speedup 1.0000x reference)
//
#include <hip/hip_runtime.h>
#include <hip/hip_bf16.h>

#define SEQ 120
#define CELLS 30          // real cells (ci<5); row ci=5 is pad-only, precomputed
#define RDIM 48
#define BQ 4096
#define MTOT (BQ*CELLS)           // 122880
#define MAIN_BLOCKS (MTOT/64)     // 1920

typedef __bf16 bf16x8 __attribute__((ext_vector_type(8)));
typedef __bf16 bf16x4 __attribute__((ext_vector_type(4)));
typedef float  f32x4  __attribute__((ext_vector_type(4)));

__device__ __forceinline__ float gelu_f(float x){
  return 0.5f * x * (1.0f + erff(x * 0.7071067811865476f));
}
__device__ __forceinline__ bf16x8 pack8(f32x4 a, f32x4 b){
  bf16x8 r;
  r[0]=(__bf16)a[0]; r[1]=(__bf16)a[1]; r[2]=(__bf16)a[2]; r[3]=(__bf16)a[3];
  r[4]=(__bf16)b[0]; r[5]=(__bf16)b[1]; r[6]=(__bf16)b[2]; r[7]=(__bf16)b[3];
  return r;
}
__device__ __forceinline__ bf16x4 pack4(f32x4 a){
  bf16x4 r;
  r[0]=(__bf16)a[0]; r[1]=(__bf16)a[1]; r[2]=(__bf16)a[2]; r[3]=(__bf16)a[3];
  return r;
}

// ---------------- prep: weight repack (fp32->bf16) + pad-cell readout Gpad ----------------
__global__ void prep_kernel(const float* __restrict__ conv_w, const float* __restrict__ conv_b,
                            const float* __restrict__ P,
                            const float* __restrict__ red_w, const float* __restrict__ red_b,
                            const float* __restrict__ res_w1, const float* __restrict__ res_w2,
                            __bf16* __restrict__ W_bt, __bf16* __restrict__ W_red,
                            __bf16* __restrict__ W1p, __bf16* __restrict__ W2p,
                            float* __restrict__ Gpad)
{
  const int b = blockIdx.x, t = threadIdx.x;
  if (b < 256){
    // W_bt[o][k], k = pos*256 + c  (pos = kh*2+kw)
    #pragma unroll
    for (int u=0;u<4;u++){
      int k = u*256 + t;
      W_bt[b*1024 + k] = (__bf16)conv_w[b*1024 + (k&255)*4 + (k>>8)];
    }
  } else if (b == 256){
    for (int i=t; i<48*256; i+=256) W_red[i] = (__bf16)red_w[i];
  } else if (b < 273){
    int l = b - 257;
    #pragma unroll
    for (int u=0;u<12;u++){
      int idx = u*256 + t;               // j*64 + k
      int j = idx >> 6, k = idx & 63;
      W1p[l*3072 + idx] = (k < 48) ? (__bf16)res_w1[(l*48+j)*48 + k] : (__bf16)0.0f;
    }
  } else if (b < 289){
    int l = b - 273;
    #pragma unroll
    for (int u=0;u<12;u++){
      int idx = u*256 + t;
      int j = idx >> 6, k = idx & 63;
      W2p[l*3072 + idx] = (k < 48) ? (__bf16)res_w2[(l*48+j)*48 + k] : (__bf16)0.0f;
    }
  } else {
    // Gpad: full fp32 readout of the all-pad patch (all 4 positions = P)
    __shared__ float tg[256];
    float z = conv_b[t];
    for (int c=0;c<256;c++){
      const float* w = conv_w + t*1024 + c*4;
      z += (w[0]+w[1]+w[2]+w[3]) * P[c];
    }
    tg[t] = gelu_f(z);
    __syncthreads();
    if (t < 48){
      float g = red_b[t];
      for (int o=0;o<256;o++) g += red_w[t*256+o]*tg[o];
      Gpad[t] = gelu_f(g);
    }
  }
}

// ---------------- main: pos-granular A staging (contiguous 1KB token reads), BK=256 per pos,
//                  bf16 A dbuf in LDS (64KB -> 2 blocks/CU), B per-wave from L2.
//                  + fused 256->48 GEMM + gelu -> G ----------------
__global__ __launch_bounds__(512, 4) void main_kernel(
    const float* __restrict__ X, const __bf16* __restrict__ W_bt,
    const float* __restrict__ conv_b, const __bf16* __restrict__ W_red,
    const float* __restrict__ red_b, float* __restrict__ G)
{
  // LDS: A bf16 dbuf [2][64 rows][512B] = 64KB; Y bf16 [64][512B] reuses [0,32K)
  __shared__ __align__(16) char sm[65536];
  const int tid  = threadIdx.x;
  const int lane = tid & 63;
  const int wave = tid >> 6;                 // 0..7; wave grid 2(M) x 4(N)
  const int wm = wave >> 2, wn = wave & 3;
  const int lr = lane & 15, lk = lane >> 4;
  const int m0 = blockIdx.x * 64;

  // A staging: instr j of wave w reads row j*8+w's token(p): 1KB CONTIGUOUS (lane*16B)
  const float* rowp[8];
  #pragma unroll
  for (int j=0;j<8;j++){
    int row = j*8 + wave;
    int m = m0 + row;
    int bs = m / 30;
    int cs = m - bs*30;
    int ci = cs/6, cj = cs - ci*6;           // ci<5 => all 4 tokens < 120
    rowp[j] = X + ((size_t)bs*SEQ + 24*ci + 2*cj)*256 + lane*4;
  }
  const __bf16* bbase[4];
  #pragma unroll
  for (int ni=0; ni<4; ++ni)
    bbase[ni] = W_bt + (size_t)(wn*64 + ni*16 + lr)*1024 + lk*8;

  f32x4 pend[8];
  f32x4 acc[2][4];
  #pragma unroll
  for (int a=0;a<2;a++)
    #pragma unroll
    for (int b=0;b<4;b++) acc[a][b] = (f32x4){0.f,0.f,0.f,0.f};

  // token float-offset for position p: ((p>>1)*12 + (p&1)) * 256
  #define POFF(p) ((((p)>>1)*12 + ((p)&1)) * 256)

  auto ISSUE = [&](int p){
    const int off = POFF(p);
    #pragma unroll
    for (int j=0;j<8;j++) pend[j] = *(const f32x4*)(rowp[j] + off);
  };
  // write pend (pos p+? data) into buffer buf: lane's 16B f32 -> 8B bf16 at swizzled slot
  auto CVTWRITE = [&](int buf){
    const int slot = lane >> 1, sub = (lane & 1) * 8;
    #pragma unroll
    for (int j=0;j<8;j++){
      int row = j*8 + wave;
      int key = (row&7)<<4;
      *(bf16x4*)(sm + buf*32768 + row*512 + (((slot*16) ^ key) + sub)) = pack4(pend[j]);
    }
  };

  ISSUE(0);
  CVTWRITE(0);
  ISSUE(1);
  __syncthreads();

  for (int p=0; p<4; ++p){
    const int buf = (p&1)*32768;
    // compute(p): 4 ck-substeps of 64, 2 ks each; B per-wave from L2 (L2-resident 512KB)
    #pragma unroll
    for (int ck=0; ck<4; ++ck){
      #pragma unroll
      for (int ks=0; ks<2; ++ks){
        bf16x8 bv[4];
        #pragma unroll
        for (int ni=0; ni<4; ++ni)
          bv[ni] = *(const bf16x8*)(bbase[ni] + p*256 + ck*64 + ks*32);
        bf16x8 av[2];
        #pragma unroll
        for (int mi=0; mi<2; ++mi){
          int row = wm*32 + mi*16 + lr;
          av[mi] = *(const bf16x8*)(sm + buf + row*512 + ((ck*128 + ks*64 + lk*16) ^ ((row&7)<<4)));
        }
        #pragma unroll
        for (int mi=0; mi<2; ++mi)
          #pragma unroll
          for (int ni=0; ni<4; ++ni)
            acc[mi][ni] = __builtin_amdgcn_mfma_f32_16x16x32_bf16(av[mi], bv[ni], acc[mi][ni], 0,0,0);
      }
    }
    if (p < 3) CVTWRITE((p+1)&1);   // write-late: pend(p+1) -> other buffer (prev barrier made it safe)
    if (p < 2) ISSUE(p+2);          // issue-early: next-next pos, full phase of latency cover
    __syncthreads();
  }

  // epilogue 1: conv bias + gelu -> Y bf16 [64][256] in LDS (row-swizzled), reusing A[0] region
  #pragma unroll
  for (int ni=0; ni<4; ++ni){
    const int col = wn*64 + ni*16 + lr;
    const float cb = conv_b[col];
    #pragma unroll
    for (int mi=0; mi<2; ++mi){
      #pragma unroll
      for (int reg=0; reg<4; ++reg){
        int row = wm*32 + mi*16 + lk*4 + reg;
        float y = gelu_f(acc[mi][ni][reg] + cb);
        *(__bf16*)(sm + ((row*512 + col*2) ^ ((row&7)<<4))) = (__bf16)y;
      }
    }
  }
  __syncthreads();

  // GEMM2: G = gelu(Y @ red_w^T + red_b); waves 0..3, wave w owns rows [w*16, w*16+16)
  if (wave < 4){
    f32x4 acc2[3];
    #pragma unroll
    for (int nf=0;nf<3;nf++) acc2[nf] = (f32x4){0.f,0.f,0.f,0.f};
    const int rowY = wave*16 + lr;
    const int keyY = (rowY&7)<<4;
    #pragma unroll
    for (int kk=0; kk<8; ++kk){
      bf16x8 a2 = *(const bf16x8*)(sm + ((rowY*512 + kk*64 + lk*16) ^ keyY));
      #pragma unroll
      for (int nf=0; nf<3; ++nf){
        bf16x8 b2 = *(const bf16x8*)(W_red + (size_t)(nf*16+lr)*256 + kk*32 + lk*8);
        acc2[nf] = __builtin_amdgcn_mfma_f32_16x16x32_bf16(a2, b2, acc2[nf], 0,0,0);
      }
    }
    #pragma unroll
    for (int nf=0; nf<3; ++nf){
      float rb = red_b[nf*16+lr];
      #pragma unroll
      for (int reg=0; reg<4; ++reg){
        int grow = m0 + wave*16 + lk*4 + reg;
        G[(size_t)grow*RDIM + nf*16 + lr] = gelu_f(acc2[nf][reg] + rb);
      }
    }
  }
}

// ---------------- head: pool + 16 residual blocks (bf16 MFMA, K padded to 64) + linear ----------------
__global__ __launch_bounds__(64) void head_kernel(
    const float* __restrict__ G, const float* __restrict__ Gpad,
    const __bf16* __restrict__ W1p, const __bf16* __restrict__ W2p,
    const float* __restrict__ res_b1, const float* __restrict__ res_b2,
    const float* __restrict__ out_w, const float* __restrict__ out_b,
    float* __restrict__ out)
{
  __shared__ __align__(16) char Hs[16*256];  // [16 rows][64 f32], swizzled, cols 48..63 = 0
  __shared__ __align__(16) char Ys[16*256];
  const int t = threadIdx.x;                 // one wave
  const int lr = t & 15, lk = t >> 4;
  const int b0 = blockIdx.x * 16;

  { // zero pad cols 48..63 (stay zero: layers only write cols<48)
    int row = t >> 2, j4 = 12 + (t & 3);
    int off = (row*256 + j4*16) ^ ((row&7)<<5);
    *(f32x4*)(Hs + off) = (f32x4){0,0,0,0};
    *(f32x4*)(Ys + off) = (f32x4){0,0,0,0};
  }

  // pool: H[b][j] = (sum_{c<30} G[b][c][j] + 6*Gpad[j]) / 36
  #pragma unroll
  for (int pp=0; pp<3; ++pp){
    int idx = pp*64 + t;
    int b = idx / 12, j4 = idx - b*12;
    f32x4 s = ((const f32x4*)Gpad)[j4] * 6.0f;
    const float* g = G + ((size_t)(b0+b)*CELLS)*RDIM + j4*4;
    #pragma unroll
    for (int c=0;c<CELLS;c++) s += *(const f32x4*)(g + c*RDIM);
    s *= (1.0f/36.0f);
    *(f32x4*)(Hs + ((b*256 + j4*16) ^ ((b&7)<<5))) = s;
  }
  __syncthreads();

  const int rowA = lr;
  const int keyA = (rowA&7)<<5;
  for (int l=0; l<16; ++l){
    bf16x8 a[2];
    #pragma unroll
    for (int kk=0;kk<2;kk++){
      f32x4 u0 = *(const f32x4*)(Hs + ((rowA*256 + kk*128 + lk*32) ^ keyA));
      f32x4 u1 = *(const f32x4*)(Hs + ((rowA*256 + kk*128 + lk*32 + 16) ^ keyA));
      a[kk] = pack8(u0,u1);
    }
    #pragma unroll
    for (int nf=0; nf<3; ++nf){
      f32x4 acc = (f32x4){0,0,0,0};
      #pragma unroll
      for (int kk=0;kk<2;kk++){
        bf16x8 bw = *(const bf16x8*)(W1p + ((size_t)l*48 + nf*16 + lr)*64 + kk*32 + lk*8);
        acc = __builtin_amdgcn_mfma_f32_16x16x32_bf16(a[kk], bw, acc, 0,0,0);
      }
      float bj = res_b1[l*48 + nf*16 + lr];
      #pragma unroll
      for (int reg=0; reg<4; ++reg){
        int row = lk*4 + reg;
        *(float*)(Ys + ((row*256 + (nf*16+lr)*4) ^ ((row&7)<<5))) = gelu_f(acc[reg] + bj);
      }
    }
    __syncthreads();
    bf16x8 a2[2];
    #pragma unroll
    for (int kk=0;kk<2;kk++){
      f32x4 u0 = *(const f32x4*)(Ys + ((rowA*256 + kk*128 + lk*32) ^ keyA));
      f32x4 u1 = *(const f32x4*)(Ys + ((rowA*256 + kk*128 + lk*32 + 16) ^ keyA));
      a2[kk] = pack8(u0,u1);
    }
    #pragma unroll
    for (int nf=0; nf<3; ++nf){
      f32x4 acc = (f32x4){0,0,0,0};
      #pragma unroll
      for (int kk=0;kk<2;kk++){
        bf16x8 bw = *(const bf16x8*)(W2p + ((size_t)l*48 + nf*16 + lr)*64 + kk*32 + lk*8);
        acc = __builtin_amdgcn_mfma_f32_16x16x32_bf16(a2[kk], bw, acc, 0,0,0);
      }
      float bj = res_b2[l*48 + nf*16 + lr];
      #pragma unroll
      for (int reg=0; reg<4; ++reg){
        int row = lk*4 + reg;
        float* hp = (float*)(Hs + ((row*256 + (nf*16+lr)*4) ^ ((row&7)<<5)));
        *hp += acc[reg] + bj;
      }
    }
    __syncthreads();
  }

  float s = 0.f;
  #pragma unroll
  for (int i=0;i<12;i++){
    int j = lk*12 + i;
    s += *(const float*)(Hs + ((lr*256 + j*4) ^ ((lr&7)<<5))) * out_w[j];
  }
  s += __shfl_xor(s, 16);
  s += __shfl_xor(s, 32);
  if (lk == 0) out[b0 + lr] = s + out_b[0];
}

extern "C" void kernel_launch(void* const* d_in, const int* in_sizes, int n_in,
                              void* d_out, int out_size, void* d_ws, size_t ws_size,
                              hipStream_t stream) {
  const float* X      = (const float*)d_in[0];
  const float* P      = (const float*)d_in[1];
  const float* conv_w = (const float*)d_in[2];
  const float* conv_b = (const float*)d_in[3];
  const float* red_w  = (const float*)d_in[4];
  const float* red_b  = (const float*)d_in[5];
  const float* res_w1 = (const float*)d_in[6];
  const float* res_b1 = (const float*)d_in[7];
  const float* res_w2 = (const float*)d_in[8];
  const float* res_b2 = (const float*)d_in[9];
  const float* out_w  = (const float*)d_in[10];
  const float* out_b  = (const float*)d_in[11];
  float* out = (float*)d_out;

  char* ws = (char*)d_ws;
  __bf16* W_bt  = (__bf16*)(ws);             // 524288 B
  __bf16* W_red = (__bf16*)(ws + 524288);    // 24576 B
  __bf16* W1p   = (__bf16*)(ws + 548864);    // 98304 B
  __bf16* W2p   = (__bf16*)(ws + 647168);    // 98304 B
  float*  Gpad  = (float*)(ws + 745472);     // 192 B
  float*  G     = (float*)(ws + 1048576);    // 23.6 MB

  prep_kernel<<<290, 256, 0, stream>>>(conv_w, conv_b, P, red_w, red_b, res_w1, res_w2,
                                       W_bt, W_red, W1p, W2p, Gpad);
  main_kernel<<<MAIN_BLOCKS, 512, 0, stream>>>(X, W_bt, conv_b, W_red, red_b, G);
  head_kernel<<<BQ/16, 64, 0, stream>>>(G, Gpad, W1p, W2p, res_b1, res_b2, out_w, out_b, out);
}